// Round 15
// baseline (407.672 us; speedup 1.0000x reference)
//
#include <hip/hip_runtime.h>
#include <math.h>

#define N 1024
#define C 384
#define H 12
#define DP 128
#define HP 144
#define MT 128  // keys per tile (2 per lane)
#define NT 8    // tiles
#define RW 2    // q-rows per wave
#define QBL 8   // q-rows per block (4 waves x 2 rows)
#define SCALING 0.17677669529663687f
#define LN_EPS 1e-5f

// ---------------- K1: fused projections GEMM (r8, unchanged) ----------------
__global__ __launch_bounds__(256) void k_qkv(
    const float* __restrict__ single,
    const float* __restrict__ Wq, const float* __restrict__ bq,
    const float* __restrict__ Wk, const float* __restrict__ bk,
    const float* __restrict__ Wv, const float* __restrict__ bv,
    const float* __restrict__ Wpq, const float* __restrict__ bpq,
    const float* __restrict__ Wpk, const float* __restrict__ bpk,
    float* __restrict__ q, float* __restrict__ kcg, float* __restrict__ v,
    float* __restrict__ qp, float* __restrict__ kp)
{
  __shared__ __align__(16) float A_s[64 * 33];
  __shared__ __align__(16) float B_s[32 * 48];
  int t = threadIdx.x;
  int nt = blockIdx.x, mt = blockIdx.y;
  int m0 = mt * 64;
  const float* W; const float* bias; int ld, kind, cb;
  if (nt < 8)       { W = Wq;  bias = bq;  ld = C;  cb = nt * 48;        kind = 0; }
  else if (nt < 16) { W = Wk;  bias = bk;  ld = C;  cb = (nt - 8) * 48;  kind = 1; }
  else if (nt < 24) { W = Wv;  bias = bv;  ld = C;  cb = (nt - 16) * 48; kind = 2; }
  else if (nt < 27) { W = Wpq; bias = bpq; ld = HP; cb = (nt - 24) * 48; kind = 3; }
  else              { W = Wpk; bias = bpk; ld = HP; cb = (nt - 27) * 48; kind = 4; }
  int tr = t >> 4, tc = t & 15;
  float acc[4][3] = {};
  for (int k0 = 0; k0 < C; k0 += 32) {
    if (k0) __syncthreads();
    #pragma unroll
    for (int i = 0; i < 8; i++) {
      int fi = i * 256 + t; int row = fi >> 5, col = fi & 31;
      A_s[row * 33 + col] = single[(m0 + row) * C + k0 + col];
    }
    #pragma unroll
    for (int i = 0; i < 6; i++) {
      int fi = i * 256 + t; int row = fi / 48, col = fi % 48;
      B_s[row * 48 + col] = W[(k0 + row) * ld + cb + col];
    }
    __syncthreads();
    #pragma unroll
    for (int k = 0; k < 32; k++) {
      float a[4], b[3];
      #pragma unroll
      for (int r = 0; r < 4; r++) a[r] = A_s[(tr * 4 + r) * 33 + k];
      #pragma unroll
      for (int c = 0; c < 3; c++) b[c] = B_s[k * 48 + tc * 3 + c];
      #pragma unroll
      for (int r = 0; r < 4; r++)
        #pragma unroll
        for (int c = 0; c < 3; c++) acc[r][c] = fmaf(a[r], b[c], acc[r][c]);
    }
  }
  #pragma unroll
  for (int c = 0; c < 3; c++) {
    int col = cb + tc * 3 + c;
    float bb = bias[col];
    #pragma unroll
    for (int r = 0; r < 4; r++) {
      int row = m0 + tr * 4 + r;
      float val = acc[r][c] + bb;
      if (kind == 0)      q[row * C + col] = val;
      else if (kind == 1) kcg[((col >> 5) * N + row) * 48 + (col & 31)] = val;
      else if (kind == 2) v[row * C + col] = val;
      else if (kind == 3) qp[row * HP + col] = val;
      else                kp[row * HP + col] = val;
    }
  }
}

// ---------------- K1b: rotate points, sq/sk sums (r8, unchanged) ----------------
__global__ __launch_bounds__(256) void k_rot(
    const float* __restrict__ qp, const float* __restrict__ kp,
    const float* __restrict__ rot,
    float* __restrict__ qg, float* __restrict__ kcg,
    float* __restrict__ sq, float* __restrict__ sknh)
{
  __shared__ __align__(16) float qp_s[HP], kp_s[HP], rot_s[9], q2_s[HP], k2_s[HP];
  int n = blockIdx.x, t = threadIdx.x;
  if (t < HP) { qp_s[t] = qp[n * HP + t]; kp_s[t] = kp[n * HP + t]; }
  if (t < 9)  rot_s[t] = rot[n * 9 + t];
  __syncthreads();
  if (t < HP) {
    int h = t / 12, r12 = t % 12, y = r12 >> 2, p = r12 & 3;
    float qgv = rot_s[y*3] * qp_s[h*12 + p] + rot_s[y*3+1] * qp_s[h*12 + 4 + p]
              + rot_s[y*3+2] * qp_s[h*12 + 8 + p];
    float kgv = rot_s[y*3] * kp_s[h*12 + p] + rot_s[y*3+1] * kp_s[h*12 + 4 + p]
              + rot_s[y*3+2] * kp_s[h*12 + 8 + p];
    qg[n * HP + t] = qgv;
    kcg[(h * N + n) * 48 + 32 + r12] = kgv;
    q2_s[t] = qgv * qgv; k2_s[t] = kgv * kgv;
  }
  if (t < 48) kcg[((t >> 2) * N + n) * 48 + 44 + (t & 3)] = 0.f;  // zero pad
  __syncthreads();
  if (t < H) {
    float s1 = 0.f, s2 = 0.f;
    #pragma unroll
    for (int e = 0; e < 12; e++) { s1 += q2_s[t * 12 + e]; s2 += k2_s[t * 12 + e]; }
    sq[n * H + t] = s1; sknh[n * H + t] = s2;
  }
}

// ---------------- K2: pair bias GEMM + rank-1 fold (r8, unchanged) ----------------
__global__ __launch_bounds__(256) void k_pb(
    const float4* __restrict__ pair4, const float* __restrict__ Wp,
    const float* __restrict__ bp, const float* __restrict__ sq,
    const float* __restrict__ sknh, float* __restrict__ pb)
{
  __shared__ __align__(16) float wp_s[12 * 128];   // [h][d]
  __shared__ __align__(16) float ob_s[12][128];
  __shared__ float sq_s[12], bp_s[12];
  int t = threadIdx.x;
  int bid = blockIdx.x;
  int n = bid >> 3;                 // 8 blocks of 128 m per n-row
  int m0 = (bid & 7) * 128;
  #pragma unroll
  for (int i = 0; i < 6; i++) {
    int fi = i * 256 + t; int h = fi >> 7, d = fi & 127;
    wp_s[h * 128 + d] = Wp[d * 12 + h];
  }
  if (t < 12) { sq_s[t] = sq[n * 12 + t]; bp_s[t] = bp[t]; }
  __syncthreads();
  int tc = t & 3, rid = t >> 2;                    // rows rid and 64+rid
  long rowA = (long)n * N + m0 + rid;
  const float4* rpA = pair4 + rowA * 32;
  const float4* rpB = rpA + 64 * 32;
  const float4* w4 = (const float4*)wp_s;          // [h][32]
  float accA[12] = {}, accB[12] = {};
  #pragma unroll
  for (int i = 0; i < 8; i++) {
    float4 a = rpA[i * 4 + tc];
    float4 b = rpB[i * 4 + tc];
    #pragma unroll
    for (int h = 0; h < 12; h++) {
      float4 w = w4[h * 32 + i * 4 + tc];
      accA[h] = fmaf(a.x, w.x, accA[h]);
      accA[h] = fmaf(a.y, w.y, accA[h]);
      accA[h] = fmaf(a.z, w.z, accA[h]);
      accA[h] = fmaf(a.w, w.w, accA[h]);
      accB[h] = fmaf(b.x, w.x, accB[h]);
      accB[h] = fmaf(b.y, w.y, accB[h]);
      accB[h] = fmaf(b.z, w.z, accB[h]);
      accB[h] = fmaf(b.w, w.w, accB[h]);
    }
  }
  #pragma unroll
  for (int h = 0; h < 12; h++) {
    accA[h] += __shfl_xor(accA[h], 1);
    accA[h] += __shfl_xor(accA[h], 2);
    accB[h] += __shfl_xor(accB[h], 1);
    accB[h] += __shfl_xor(accB[h], 2);
  }
  if (tc == 0) {
    float skrA[12], skrB[12];
    #pragma unroll
    for (int i = 0; i < 3; i++) {
      *(float4*)&skrA[i * 4] = *(const float4*)&sknh[(m0 + rid) * 12 + i * 4];
      *(float4*)&skrB[i * 4] = *(const float4*)&sknh[(m0 + 64 + rid) * 12 + i * 4];
    }
    #pragma unroll
    for (int h = 0; h < 12; h++) {
      ob_s[h][rid]      = accA[h] + bp_s[h] - 0.5f * SCALING * (sq_s[h] + skrA[h]);
      ob_s[h][64 + rid] = accB[h] + bp_s[h] - 0.5f * SCALING * (sq_s[h] + skrB[h]);
    }
  }
  __syncthreads();
  #pragma unroll
  for (int i = 0; i < 6; i++) {
    int idx = i * 256 + t; int h = idx >> 7, r = idx & 127;
    pb[(long)h * (N * (long)N) + (long)n * N + m0 + r] = ob_s[h][r];
  }
}

// ---------------- K3: flash attention v15 = r14 + MT=128 (qc amortized 2x) ----------------
// Each lane handles keys m=lane and m=lane+64; both accumulate into the SAME
// o_[2][32], so the loop-invariant qc broadcasts (the largest DS slice) are
// read once per 128 keys instead of per 64. DS instr per 128 keys: 92 -> 70.
// Single-buffered 49.5 KB (3 blocks/CU), 2 barriers per 128-key tile (same
// total barrier count as r14). Second-half LDS reads are fixed +16KB/+8KB
// offsets off the same base address.
__global__ __launch_bounds__(256) void k_attn(
    const float* __restrict__ q, const float* __restrict__ qg,
    const float* __restrict__ kcg, const float* __restrict__ v,
    const float* __restrict__ pb, float* __restrict__ wt)
{
  __shared__ __align__(16) float kc_s[128 * 64];   // [m][12 chunks], XOR (m&7)
  __shared__ __align__(16) float v_s[128 * 32];    // [m][8 chunks],  XOR (m&7)
  __shared__ __align__(16) float qc_s[QBL][48];    // S-prescaled [q|qg|0]

  int t = threadIdx.x;
  int bid = blockIdx.x;
  int s = (bid & 7) * 192 + (bid >> 3);   // 1.5 heads per XCD
  int h = s >> 7, qb = s & 127;
  int q0 = qb * QBL;
  int w = t >> 6, lane = t & 63;
  long pbbase = (long)h * (N * (long)N);
  const float* kch = kcg + (long)h * N * 48;
  int hc32 = h * 32;
  int w2 = w * 2;

  // staging job coords (static per-thread)
  int krow[6], kc4o[6], kdst[6];
  #pragma unroll
  for (int i = 0; i < 6; i++) {
    int f = i * 256 + t; krow[i] = f / 12; kc4o[i] = f % 12;
    kdst[i] = krow[i] * 64 + ((kc4o[i] ^ (krow[i] & 7)) << 2);
  }
  int vrow[4], vc4[4], vdst[4];
  #pragma unroll
  for (int i = 0; i < 4; i++) {
    int f = i * 256 + t; vrow[i] = f >> 3; vc4[i] = f & 7;
    vdst[i] = vrow[i] * 32 + ((vc4[i] ^ (vrow[i] & 7)) << 2);
  }

  float4 pk[6], pv[4];
  float pb_cur[2][2], pb_nxt[2][2];    // [row][m-half]

#define STAGE_LOAD(M0) \
  { _Pragma("unroll") \
    for (int i = 0; i < 6; i++) \
      pk[i] = *(const float4*)&kch[((M0) + krow[i]) * 48 + kc4o[i] * 4]; \
    _Pragma("unroll") \
    for (int i = 0; i < 4; i++) \
      pv[i] = *(const float4*)&v[((M0) + vrow[i]) * C + hc32 + vc4[i] * 4]; }

#define STAGE_WRITE() \
  { _Pragma("unroll") \
    for (int i = 0; i < 6; i++) *(float4*)&kc_s[kdst[i]] = pk[i]; \
    _Pragma("unroll") \
    for (int i = 0; i < 4; i++) *(float4*)&v_s[vdst[i]] = pv[i]; }

  const float* pbp = pb + pbbase + (long)(q0 + w2) * N + lane;

  // prologue: stage tile 0, build qc, load pb tile 0
  STAGE_LOAD(0);
  #pragma unroll
  for (int r = 0; r < RW; r++) {
    pb_cur[r][0] = pbp[r * N];
    pb_cur[r][1] = pbp[r * N + 64];
  }
  if (t < QBL * 12) {
    int r = t / 12, c4 = t % 12;
    float4 val;
    if (c4 < 8)       val = *(const float4*)&q[(q0 + r) * C + hc32 + c4 * 4];
    else if (c4 < 11) val = *(const float4*)&qg[(q0 + r) * HP + h * 12 + (c4 - 8) * 4];
    else              val = make_float4(0.f, 0.f, 0.f, 0.f);
    val.x *= SCALING; val.y *= SCALING; val.z *= SCALING; val.w *= SCALING;
    *(float4*)&qc_s[r][c4 * 4] = val;
  }
  STAGE_WRITE();
  __syncthreads();

  float lsum0 = 0.f, lsum1 = 0.f;
  float o_[2][32] = {};

  for (int tile = 0; tile < NT; tile++) {
    int m0 = tile * MT;
    if (tile < NT - 1) {
      STAGE_LOAD(m0 + MT);
      #pragma unroll
      for (int r = 0; r < RW; r++) {
        pb_nxt[r][0] = pbp[r * N + m0 + MT];
        pb_nxt[r][1] = pbp[r * N + m0 + MT + 64];
      }
    }
    // ---- QK both halves (lane=m, m+64): 22 swizzled b128 + 22 broadcasts ----
    float L0a = pb_cur[0][0], L0b = pb_cur[0][1];
    float L1a = pb_cur[1][0], L1b = pb_cur[1][1];
    #pragma unroll
    for (int c4 = 0; c4 < 11; c4++) {
      int base = lane * 64 + ((c4 ^ (lane & 7)) << 2);
      float4 kva = *(const float4*)&kc_s[base];
      float4 kvb = *(const float4*)&kc_s[base + 64 * 64];
      float4 qv0 = *(const float4*)&qc_s[w2][c4 * 4];
      float4 qv1 = *(const float4*)&qc_s[w2 + 1][c4 * 4];
      L0a = fmaf(qv0.x, kva.x, L0a); L0a = fmaf(qv0.y, kva.y, L0a);
      L0a = fmaf(qv0.z, kva.z, L0a); L0a = fmaf(qv0.w, kva.w, L0a);
      L0b = fmaf(qv0.x, kvb.x, L0b); L0b = fmaf(qv0.y, kvb.y, L0b);
      L0b = fmaf(qv0.z, kvb.z, L0b); L0b = fmaf(qv0.w, kvb.w, L0b);
      L1a = fmaf(qv1.x, kva.x, L1a); L1a = fmaf(qv1.y, kva.y, L1a);
      L1a = fmaf(qv1.z, kva.z, L1a); L1a = fmaf(qv1.w, kva.w, L1a);
      L1b = fmaf(qv1.x, kvb.x, L1b); L1b = fmaf(qv1.y, kvb.y, L1b);
      L1b = fmaf(qv1.z, kvb.z, L1b); L1b = fmaf(qv1.w, kvb.w, L1b);
    }
    float p0a = __expf(L0a), p0b = __expf(L0b);   // max-free (validated r7/r8)
    float p1a = __expf(L1a), p1b = __expf(L1b);
    lsum0 += p0a + p0b; lsum1 += p1a + p1b;
    // ---- AV both halves: 16 swizzled b128, p in regs, o_ shared over m ----
    #pragma unroll
    for (int c4 = 0; c4 < 8; c4++) {
      int vb = lane * 32 + ((c4 ^ (lane & 7)) << 2);
      float4 va = *(const float4*)&v_s[vb];
      float4 vbh = *(const float4*)&v_s[vb + 64 * 32];
      o_[0][c4*4+0] = fmaf(p0a, va.x, fmaf(p0b, vbh.x, o_[0][c4*4+0]));
      o_[0][c4*4+1] = fmaf(p0a, va.y, fmaf(p0b, vbh.y, o_[0][c4*4+1]));
      o_[0][c4*4+2] = fmaf(p0a, va.z, fmaf(p0b, vbh.z, o_[0][c4*4+2]));
      o_[0][c4*4+3] = fmaf(p0a, va.w, fmaf(p0b, vbh.w, o_[0][c4*4+3]));
      o_[1][c4*4+0] = fmaf(p1a, va.x, fmaf(p1b, vbh.x, o_[1][c4*4+0]));
      o_[1][c4*4+1] = fmaf(p1a, va.y, fmaf(p1b, vbh.y, o_[1][c4*4+1]));
      o_[1][c4*4+2] = fmaf(p1a, va.z, fmaf(p1b, vbh.z, o_[1][c4*4+2]));
      o_[1][c4*4+3] = fmaf(p1a, va.w, fmaf(p1b, vbh.w, o_[1][c4*4+3]));
    }
    __syncthreads();                 // all reads of kc_s/v_s done (WAR)
    if (tile < NT - 1) {
      STAGE_WRITE();
      #pragma unroll
      for (int r = 0; r < RW; r++) {
        pb_cur[r][0] = pb_nxt[r][0];
        pb_cur[r][1] = pb_nxt[r][1];
      }
    }
    __syncthreads();                 // writes visible (RAW)
  }

  #pragma unroll
  for (int off = 32; off; off >>= 1) {
    lsum0 += __shfl_xor(lsum0, off);
    lsum1 += __shfl_xor(lsum1, off);
  }
  // butterfly transpose-reduce (r10-proven): col c sum lands at lane c (c<32)
  #pragma unroll
  for (int r = 0; r < 2; r++) {
    float c16[16], c8[8], c4a[4], c2[2], c1;
    int b = lane & 1;
    #pragma unroll
    for (int j = 0; j < 16; j++) {
      float keep = b ? o_[r][2*j+1] : o_[r][2*j];
      float send = b ? o_[r][2*j]   : o_[r][2*j+1];
      c16[j] = keep + __shfl_xor(send, 1);
    }
    b = lane & 2;
    #pragma unroll
    for (int j = 0; j < 8; j++) {
      float keep = b ? c16[2*j+1] : c16[2*j];
      float send = b ? c16[2*j]   : c16[2*j+1];
      c8[j] = keep + __shfl_xor(send, 2);
    }
    b = lane & 4;
    #pragma unroll
    for (int j = 0; j < 4; j++) {
      float keep = b ? c8[2*j+1] : c8[2*j];
      float send = b ? c8[2*j]   : c8[2*j+1];
      c4a[j] = keep + __shfl_xor(send, 4);
    }
    b = lane & 8;
    #pragma unroll
    for (int j = 0; j < 2; j++) {
      float keep = b ? c4a[2*j+1] : c4a[2*j];
      float send = b ? c4a[2*j]   : c4a[2*j+1];
      c2[j] = keep + __shfl_xor(send, 8);
    }
    b = lane & 16;
    {
      float keep = b ? c2[1] : c2[0];
      float send = b ? c2[0] : c2[1];
      c1 = keep + __shfl_xor(send, 16);
    }
    c1 += __shfl_xor(c1, 32);
    float ls = (r == 0) ? lsum0 : lsum1;
    if (lane < 32) wt[(q0 + w2 + r) * C + hc32 + lane] = c1 / ls;
  }
#undef STAGE_LOAD
#undef STAGE_WRITE
}

// ---------------- K4: output GEMM + residual + LayerNorm (r8, unchanged) ----------------
__global__ __launch_bounds__(384) void k_out(
    const float* __restrict__ wt, const float* __restrict__ Wo,
    const float* __restrict__ bo, const float* __restrict__ single,
    const float* __restrict__ gamma, const float* __restrict__ beta,
    float* __restrict__ out)
{
  __shared__ __align__(16) float wt_s[4 * C];
  __shared__ __align__(16) float red[4][2][6];
  int t = threadIdx.x, n0 = blockIdx.x * 4;
  for (int idx = t; idx < 4 * C; idx += 384) wt_s[idx] = wt[n0 * C + idx];
  __syncthreads();
  float acc[4] = {};
  for (int ck = 0; ck < C; ck++) {
    float w = Wo[ck * C + t];
    #pragma unroll
    for (int i = 0; i < 4; i++) acc[i] = fmaf(wt_s[i * C + ck], w, acc[i]);
  }
  float x[4], bov = bo[t];
  #pragma unroll
  for (int i = 0; i < 4; i++) x[i] = single[(n0 + i) * C + t] + acc[i] + bov;
  int wid = t >> 6, lane = t & 63;
  #pragma unroll
  for (int i = 0; i < 4; i++) {
    float s = x[i], s2 = x[i] * x[i];
    #pragma unroll
    for (int off = 32; off; off >>= 1) { s += __shfl_xor(s, off); s2 += __shfl_xor(s2, off); }
    if (lane == 0) { red[i][0][wid] = s; red[i][1][wid] = s2; }
  }
  __syncthreads();
  float gv = gamma[t], bv = beta[t];
  #pragma unroll
  for (int i = 0; i < 4; i++) {
    float S = 0.f, S2 = 0.f;
    #pragma unroll
    for (int w = 0; w < 6; w++) { S += red[i][0][w]; S2 += red[i][1][w]; }
    float mu = S * (1.0f / C);
    float var = S2 * (1.0f / C) - mu * mu;
    out[(n0 + i) * C + t] = (x[i] - mu) * rsqrtf(var + LN_EPS) * gv + bv;
  }
}

extern "C" void kernel_launch(void* const* d_in, const int* in_sizes, int n_in,
                              void* d_out, int out_size, void* d_ws, size_t ws_size,
                              hipStream_t stream) {
  const float* single = (const float*)d_in[0];
  const float* pair   = (const float*)d_in[1];
  const float* rot    = (const float*)d_in[2];
  const float* Wq  = (const float*)d_in[4];  const float* bq  = (const float*)d_in[5];
  const float* Wk  = (const float*)d_in[6];  const float* bk  = (const float*)d_in[7];
  const float* Wv  = (const float*)d_in[8];  const float* bv  = (const float*)d_in[9];
  const float* Wp  = (const float*)d_in[10]; const float* bp  = (const float*)d_in[11];
  const float* Wpq = (const float*)d_in[12]; const float* bpq = (const float*)d_in[13];
  const float* Wpk = (const float*)d_in[14]; const float* bpk = (const float*)d_in[15];
  const float* Wo  = (const float*)d_in[16]; const float* bo  = (const float*)d_in[17];
  const float* gamma = (const float*)d_in[18]; const float* beta = (const float*)d_in[19];

  float* ws   = (float*)d_ws;
  float* pb   = ws;                          // [12][N*N]
  float* q    = pb + 12L * N * N;            // [N][C]
  float* v    = q + N * C;                   // [N][C]
  float* qp   = v + N * C;                   // [N][HP]
  float* kp   = qp + N * HP;                 // [N][HP]
  float* qg   = kp + N * HP;                 // [N][HP]
  float* kcg  = qg + N * HP;                 // [12][N][48]
  float* sq   = kcg + 12L * N * 48;          // [N][12]
  float* sknh = sq + N * H;                  // [N][12]
  float* wt   = sknh + N * H;                // [N][C]

  k_qkv<<<dim3(30, 16), 256, 0, stream>>>(single, Wq, bq, Wk, bk, Wv, bv,
                                          Wpq, bpq, Wpk, bpk, q, kcg, v, qp, kp);
  k_rot<<<N, 256, 0, stream>>>(qp, kp, rot, qg, kcg, sq, sknh);
  k_pb<<<8192, 256, 0, stream>>>((const float4*)pair, Wp, bp, sq, sknh, pb);
  k_attn<<<1536, 256, 0, stream>>>(q, qg, kcg, v, pb, wt);
  k_out<<<256, 384, 0, stream>>>(wt, Wo, bo, single, gamma, beta, (float*)d_out);
}

// Round 16
// 270.185 us; speedup vs baseline: 1.5089x; 1.5089x over previous
//
#include <hip/hip_runtime.h>
#include <math.h>

#define N 1024
#define C 384
#define H 12
#define DP 128
#define HP 144
#define MT 64   // keys per tile
#define NT 16   // tiles
#define RW 2    // q-rows per wave
#define QBL 8   // q-rows per block (4 waves x 2 rows)
#define SCALING 0.17677669529663687f
#define LN_EPS 1e-5f

// ---------------- K1: fused projections GEMM (r8, unchanged) ----------------
__global__ __launch_bounds__(256) void k_qkv(
    const float* __restrict__ single,
    const float* __restrict__ Wq, const float* __restrict__ bq,
    const float* __restrict__ Wk, const float* __restrict__ bk,
    const float* __restrict__ Wv, const float* __restrict__ bv,
    const float* __restrict__ Wpq, const float* __restrict__ bpq,
    const float* __restrict__ Wpk, const float* __restrict__ bpk,
    float* __restrict__ q, float* __restrict__ kcg, float* __restrict__ v,
    float* __restrict__ qp, float* __restrict__ kp)
{
  __shared__ __align__(16) float A_s[64 * 33];
  __shared__ __align__(16) float B_s[32 * 48];
  int t = threadIdx.x;
  int nt = blockIdx.x, mt = blockIdx.y;
  int m0 = mt * 64;
  const float* W; const float* bias; int ld, kind, cb;
  if (nt < 8)       { W = Wq;  bias = bq;  ld = C;  cb = nt * 48;        kind = 0; }
  else if (nt < 16) { W = Wk;  bias = bk;  ld = C;  cb = (nt - 8) * 48;  kind = 1; }
  else if (nt < 24) { W = Wv;  bias = bv;  ld = C;  cb = (nt - 16) * 48; kind = 2; }
  else if (nt < 27) { W = Wpq; bias = bpq; ld = HP; cb = (nt - 24) * 48; kind = 3; }
  else              { W = Wpk; bias = bpk; ld = HP; cb = (nt - 27) * 48; kind = 4; }
  int tr = t >> 4, tc = t & 15;
  float acc[4][3] = {};
  for (int k0 = 0; k0 < C; k0 += 32) {
    if (k0) __syncthreads();
    #pragma unroll
    for (int i = 0; i < 8; i++) {
      int fi = i * 256 + t; int row = fi >> 5, col = fi & 31;
      A_s[row * 33 + col] = single[(m0 + row) * C + k0 + col];
    }
    #pragma unroll
    for (int i = 0; i < 6; i++) {
      int fi = i * 256 + t; int row = fi / 48, col = fi % 48;
      B_s[row * 48 + col] = W[(k0 + row) * ld + cb + col];
    }
    __syncthreads();
    #pragma unroll
    for (int k = 0; k < 32; k++) {
      float a[4], b[3];
      #pragma unroll
      for (int r = 0; r < 4; r++) a[r] = A_s[(tr * 4 + r) * 33 + k];
      #pragma unroll
      for (int c = 0; c < 3; c++) b[c] = B_s[k * 48 + tc * 3 + c];
      #pragma unroll
      for (int r = 0; r < 4; r++)
        #pragma unroll
        for (int c = 0; c < 3; c++) acc[r][c] = fmaf(a[r], b[c], acc[r][c]);
    }
  }
  #pragma unroll
  for (int c = 0; c < 3; c++) {
    int col = cb + tc * 3 + c;
    float bb = bias[col];
    #pragma unroll
    for (int r = 0; r < 4; r++) {
      int row = m0 + tr * 4 + r;
      float val = acc[r][c] + bb;
      if (kind == 0)      q[row * C + col] = val;
      else if (kind == 1) kcg[((col >> 5) * N + row) * 48 + (col & 31)] = val;
      else if (kind == 2) v[row * C + col] = val;
      else if (kind == 3) qp[row * HP + col] = val;
      else                kp[row * HP + col] = val;
    }
  }
}

// ---------------- K1b: rotate points, sq/sk sums (r8, unchanged) ----------------
__global__ __launch_bounds__(256) void k_rot(
    const float* __restrict__ qp, const float* __restrict__ kp,
    const float* __restrict__ rot,
    float* __restrict__ qg, float* __restrict__ kcg,
    float* __restrict__ sq, float* __restrict__ sknh)
{
  __shared__ __align__(16) float qp_s[HP], kp_s[HP], rot_s[9], q2_s[HP], k2_s[HP];
  int n = blockIdx.x, t = threadIdx.x;
  if (t < HP) { qp_s[t] = qp[n * HP + t]; kp_s[t] = kp[n * HP + t]; }
  if (t < 9)  rot_s[t] = rot[n * 9 + t];
  __syncthreads();
  if (t < HP) {
    int h = t / 12, r12 = t % 12, y = r12 >> 2, p = r12 & 3;
    float qgv = rot_s[y*3] * qp_s[h*12 + p] + rot_s[y*3+1] * qp_s[h*12 + 4 + p]
              + rot_s[y*3+2] * qp_s[h*12 + 8 + p];
    float kgv = rot_s[y*3] * kp_s[h*12 + p] + rot_s[y*3+1] * kp_s[h*12 + 4 + p]
              + rot_s[y*3+2] * kp_s[h*12 + 8 + p];
    qg[n * HP + t] = qgv;
    kcg[(h * N + n) * 48 + 32 + r12] = kgv;
    q2_s[t] = qgv * qgv; k2_s[t] = kgv * kgv;
  }
  if (t < 48) kcg[((t >> 2) * N + n) * 48 + 44 + (t & 3)] = 0.f;  // zero pad
  __syncthreads();
  if (t < H) {
    float s1 = 0.f, s2 = 0.f;
    #pragma unroll
    for (int e = 0; e < 12; e++) { s1 += q2_s[t * 12 + e]; s2 += k2_s[t * 12 + e]; }
    sq[n * H + t] = s1; sknh[n * H + t] = s2;
  }
}

// ---------------- K2: pair bias GEMM + rank-1 fold (r8, unchanged) ----------------
__global__ __launch_bounds__(256) void k_pb(
    const float4* __restrict__ pair4, const float* __restrict__ Wp,
    const float* __restrict__ bp, const float* __restrict__ sq,
    const float* __restrict__ sknh, float* __restrict__ pb)
{
  __shared__ __align__(16) float wp_s[12 * 128];   // [h][d]
  __shared__ __align__(16) float ob_s[12][128];
  __shared__ float sq_s[12], bp_s[12];
  int t = threadIdx.x;
  int bid = blockIdx.x;
  int n = bid >> 3;                 // 8 blocks of 128 m per n-row
  int m0 = (bid & 7) * 128;
  #pragma unroll
  for (int i = 0; i < 6; i++) {
    int fi = i * 256 + t; int h = fi >> 7, d = fi & 127;
    wp_s[h * 128 + d] = Wp[d * 12 + h];
  }
  if (t < 12) { sq_s[t] = sq[n * 12 + t]; bp_s[t] = bp[t]; }
  __syncthreads();
  int tc = t & 3, rid = t >> 2;                    // rows rid and 64+rid
  long rowA = (long)n * N + m0 + rid;
  const float4* rpA = pair4 + rowA * 32;
  const float4* rpB = rpA + 64 * 32;
  const float4* w4 = (const float4*)wp_s;          // [h][32]
  float accA[12] = {}, accB[12] = {};
  #pragma unroll
  for (int i = 0; i < 8; i++) {
    float4 a = rpA[i * 4 + tc];
    float4 b = rpB[i * 4 + tc];
    #pragma unroll
    for (int h = 0; h < 12; h++) {
      float4 w = w4[h * 32 + i * 4 + tc];
      accA[h] = fmaf(a.x, w.x, accA[h]);
      accA[h] = fmaf(a.y, w.y, accA[h]);
      accA[h] = fmaf(a.z, w.z, accA[h]);
      accA[h] = fmaf(a.w, w.w, accA[h]);
      accB[h] = fmaf(b.x, w.x, accB[h]);
      accB[h] = fmaf(b.y, w.y, accB[h]);
      accB[h] = fmaf(b.z, w.z, accB[h]);
      accB[h] = fmaf(b.w, w.w, accB[h]);
    }
  }
  #pragma unroll
  for (int h = 0; h < 12; h++) {
    accA[h] += __shfl_xor(accA[h], 1);
    accA[h] += __shfl_xor(accA[h], 2);
    accB[h] += __shfl_xor(accB[h], 1);
    accB[h] += __shfl_xor(accB[h], 2);
  }
  if (tc == 0) {
    float skrA[12], skrB[12];
    #pragma unroll
    for (int i = 0; i < 3; i++) {
      *(float4*)&skrA[i * 4] = *(const float4*)&sknh[(m0 + rid) * 12 + i * 4];
      *(float4*)&skrB[i * 4] = *(const float4*)&sknh[(m0 + 64 + rid) * 12 + i * 4];
    }
    #pragma unroll
    for (int h = 0; h < 12; h++) {
      ob_s[h][rid]      = accA[h] + bp_s[h] - 0.5f * SCALING * (sq_s[h] + skrA[h]);
      ob_s[h][64 + rid] = accB[h] + bp_s[h] - 0.5f * SCALING * (sq_s[h] + skrB[h]);
    }
  }
  __syncthreads();
  #pragma unroll
  for (int i = 0; i < 6; i++) {
    int idx = i * 256 + t; int h = idx >> 7, r = idx & 127;
    pb[(long)h * (N * (long)N) + (long)n * N + m0 + r] = ob_s[h][r];
  }
}

// ---------------- K3: flash attention v16 = r13 + __launch_bounds__(256,4) ----------------
// r15 post-mortem: r13/r14 sat at ~140 VGPR -> >128 cliff -> only 8 waves/CU
// (2 blocks). This variant is the low-register r13 structure (MT=64,
// single-buffered 26 KB LDS) with the allocator capped at 128 VGPR via
// launch_bounds(256,4): 16 waves/CU = 4 blocks/CU (4 x 26 KB = 104 KB LDS).
// Doubled residency attacks the measured latency-hiding starvation.
__global__ __launch_bounds__(256, 4) void k_attn(
    const float* __restrict__ q, const float* __restrict__ qg,
    const float* __restrict__ kcg, const float* __restrict__ v,
    const float* __restrict__ pb, float* __restrict__ wt)
{
  __shared__ __align__(16) float kc_s[64 * 64];    // [m][12 chunks], XOR (m&7)
  __shared__ __align__(16) float v_s[64 * 32];     // [m][8 chunks],  XOR (m&7)
  __shared__ __align__(16) float qc_s[QBL][48];    // S-prescaled [q|qg|0]

  int t = threadIdx.x;
  int bid = blockIdx.x;
  int s = (bid & 7) * 192 + (bid >> 3);   // 1.5 heads per XCD
  int h = s >> 7, qb = s & 127;
  int q0 = qb * QBL;
  int w = t >> 6, lane = t & 63;
  long pbbase = (long)h * (N * (long)N);
  const float* kch = kcg + (long)h * N * 48;
  int hc32 = h * 32;
  int mr = t >> 3, c4v = t & 7;
  int w2 = w * 2;

  float4 pk0, pk1, pk2, pv0, pv1;
  float pb_cur[RW], pb_nxt[RW];

#define STAGE_LOAD(M0) \
  { int f0 = t, f1 = 256 + t, f2 = 512 + t; \
    pk0 = *(const float4*)&kch[((M0) + f0 / 12) * 48 + (f0 % 12) * 4]; \
    pk1 = *(const float4*)&kch[((M0) + f1 / 12) * 48 + (f1 % 12) * 4]; \
    pk2 = *(const float4*)&kch[((M0) + f2 / 12) * 48 + (f2 % 12) * 4]; \
    pv0 = *(const float4*)&v[((M0) + mr) * C + hc32 + c4v * 4]; \
    pv1 = *(const float4*)&v[((M0) + 32 + mr) * C + hc32 + c4v * 4]; }

#define ST_KC(F, VAL) \
  { int row_ = (F) / 12, c4_ = (F) % 12; \
    *(float4*)&kc_s[row_ * 64 + ((c4_ ^ (row_ & 7)) << 2)] = VAL; }
#define ST_V(MM, VAL) \
  *(float4*)&v_s[(MM) * 32 + ((c4v ^ ((MM) & 7)) << 2)] = VAL;

#define STAGE_WRITE() \
  { ST_KC(t, pk0) ST_KC(256 + t, pk1) ST_KC(512 + t, pk2) \
    ST_V(mr, pv0) ST_V(32 + mr, pv1) }

  // prologue: stage tile 0, build qc, load pb chunk 0
  STAGE_LOAD(0);
  #pragma unroll
  for (int r = 0; r < RW; r++)
    pb_cur[r] = pb[pbbase + (long)(q0 + w2 + r) * N + lane];
  if (t < QBL * 12) {
    int r = t / 12, c4 = t % 12;
    float4 val;
    if (c4 < 8)       val = *(const float4*)&q[(q0 + r) * C + hc32 + c4 * 4];
    else if (c4 < 11) val = *(const float4*)&qg[(q0 + r) * HP + h * 12 + (c4 - 8) * 4];
    else              val = make_float4(0.f, 0.f, 0.f, 0.f);
    val.x *= SCALING; val.y *= SCALING; val.z *= SCALING; val.w *= SCALING;
    *(float4*)&qc_s[r][c4 * 4] = val;
  }
  STAGE_WRITE();
  __syncthreads();

  float lsum0 = 0.f, lsum1 = 0.f;
  float o_[2][32] = {};

  for (int tile = 0; tile < NT; tile++) {
    int m0 = tile * MT;
    if (tile < NT - 1) {
      STAGE_LOAD(m0 + MT);
      #pragma unroll
      for (int r = 0; r < RW; r++)
        pb_nxt[r] = pb[pbbase + (long)(q0 + w2 + r) * N + m0 + MT + lane];
    }
    // ---- QK (lane=m): 11 swizzled b128 + 22 broadcasts ----
    float L0 = pb_cur[0], L1 = pb_cur[1];
    #pragma unroll
    for (int c4 = 0; c4 < 11; c4++) {
      float4 kv = *(const float4*)&kc_s[lane * 64 + ((c4 ^ (lane & 7)) << 2)];
      float4 qv0 = *(const float4*)&qc_s[w2][c4 * 4];
      float4 qv1 = *(const float4*)&qc_s[w2 + 1][c4 * 4];
      L0 = fmaf(qv0.x, kv.x, L0); L0 = fmaf(qv0.y, kv.y, L0);
      L0 = fmaf(qv0.z, kv.z, L0); L0 = fmaf(qv0.w, kv.w, L0);
      L1 = fmaf(qv1.x, kv.x, L1); L1 = fmaf(qv1.y, kv.y, L1);
      L1 = fmaf(qv1.z, kv.z, L1); L1 = fmaf(qv1.w, kv.w, L1);
    }
    float p0 = __expf(L0), p1 = __expf(L1);   // max-free (validated r7/r8)
    lsum0 += p0; lsum1 += p1;
    // ---- AV (lane=m): 8 swizzled b128, p in registers, o_ private ----
    #pragma unroll
    for (int c4 = 0; c4 < 8; c4++) {
      float4 vv = *(const float4*)&v_s[lane * 32 + ((c4 ^ (lane & 7)) << 2)];
      o_[0][c4*4+0] = fmaf(p0, vv.x, o_[0][c4*4+0]);
      o_[0][c4*4+1] = fmaf(p0, vv.y, o_[0][c4*4+1]);
      o_[0][c4*4+2] = fmaf(p0, vv.z, o_[0][c4*4+2]);
      o_[0][c4*4+3] = fmaf(p0, vv.w, o_[0][c4*4+3]);
      o_[1][c4*4+0] = fmaf(p1, vv.x, o_[1][c4*4+0]);
      o_[1][c4*4+1] = fmaf(p1, vv.y, o_[1][c4*4+1]);
      o_[1][c4*4+2] = fmaf(p1, vv.z, o_[1][c4*4+2]);
      o_[1][c4*4+3] = fmaf(p1, vv.w, o_[1][c4*4+3]);
    }
    __syncthreads();                 // all reads of kc_s/v_s done
    if (tile < NT - 1) {
      STAGE_WRITE();
      #pragma unroll
      for (int r = 0; r < RW; r++) pb_cur[r] = pb_nxt[r];
    }
    __syncthreads();                 // writes visible for next tile
  }

  #pragma unroll
  for (int off = 32; off; off >>= 1) {
    lsum0 += __shfl_xor(lsum0, off);
    lsum1 += __shfl_xor(lsum1, off);
  }
  // butterfly transpose-reduce (r10-proven): col c sum lands at lane c (c<32)
  #pragma unroll
  for (int r = 0; r < 2; r++) {
    float c16[16], c8[8], c4a[4], c2[2], c1;
    int b = lane & 1;
    #pragma unroll
    for (int j = 0; j < 16; j++) {
      float keep = b ? o_[r][2*j+1] : o_[r][2*j];
      float send = b ? o_[r][2*j]   : o_[r][2*j+1];
      c16[j] = keep + __shfl_xor(send, 1);
    }
    b = lane & 2;
    #pragma unroll
    for (int j = 0; j < 8; j++) {
      float keep = b ? c16[2*j+1] : c16[2*j];
      float send = b ? c16[2*j]   : c16[2*j+1];
      c8[j] = keep + __shfl_xor(send, 2);
    }
    b = lane & 4;
    #pragma unroll
    for (int j = 0; j < 4; j++) {
      float keep = b ? c8[2*j+1] : c8[2*j];
      float send = b ? c8[2*j]   : c8[2*j+1];
      c4a[j] = keep + __shfl_xor(send, 4);
    }
    b = lane & 8;
    #pragma unroll
    for (int j = 0; j < 2; j++) {
      float keep = b ? c4a[2*j+1] : c4a[2*j];
      float send = b ? c4a[2*j]   : c4a[2*j+1];
      c2[j] = keep + __shfl_xor(send, 8);
    }
    b = lane & 16;
    {
      float keep = b ? c2[1] : c2[0];
      float send = b ? c2[0] : c2[1];
      c1 = keep + __shfl_xor(send, 16);
    }
    c1 += __shfl_xor(c1, 32);
    float ls = (r == 0) ? lsum0 : lsum1;
    if (lane < 32) wt[(q0 + w2 + r) * C + hc32 + lane] = c1 / ls;
  }
#undef STAGE_LOAD
#undef STAGE_WRITE
#undef ST_KC
#undef ST_V
}

// ---------------- K4: output GEMM + residual + LayerNorm (r8, unchanged) ----------------
__global__ __launch_bounds__(384) void k_out(
    const float* __restrict__ wt, const float* __restrict__ Wo,
    const float* __restrict__ bo, const float* __restrict__ single,
    const float* __restrict__ gamma, const float* __restrict__ beta,
    float* __restrict__ out)
{
  __shared__ __align__(16) float wt_s[4 * C];
  __shared__ __align__(16) float red[4][2][6];
  int t = threadIdx.x, n0 = blockIdx.x * 4;
  for (int idx = t; idx < 4 * C; idx += 384) wt_s[idx] = wt[n0 * C + idx];
  __syncthreads();
  float acc[4] = {};
  for (int ck = 0; ck < C; ck++) {
    float w = Wo[ck * C + t];
    #pragma unroll
    for (int i = 0; i < 4; i++) acc[i] = fmaf(wt_s[i * C + ck], w, acc[i]);
  }
  float x[4], bov = bo[t];
  #pragma unroll
  for (int i = 0; i < 4; i++) x[i] = single[(n0 + i) * C + t] + acc[i] + bov;
  int wid = t >> 6, lane = t & 63;
  #pragma unroll
  for (int i = 0; i < 4; i++) {
    float s = x[i], s2 = x[i] * x[i];
    #pragma unroll
    for (int off = 32; off; off >>= 1) { s += __shfl_xor(s, off); s2 += __shfl_xor(s2, off); }
    if (lane == 0) { red[i][0][wid] = s; red[i][1][wid] = s2; }
  }
  __syncthreads();
  float gv = gamma[t], bv = beta[t];
  #pragma unroll
  for (int i = 0; i < 4; i++) {
    float S = 0.f, S2 = 0.f;
    #pragma unroll
    for (int w = 0; w < 6; w++) { S += red[i][0][w]; S2 += red[i][1][w]; }
    float mu = S * (1.0f / C);
    float var = S2 * (1.0f / C) - mu * mu;
    out[(n0 + i) * C + t] = (x[i] - mu) * rsqrtf(var + LN_EPS) * gv + bv;
  }
}

extern "C" void kernel_launch(void* const* d_in, const int* in_sizes, int n_in,
                              void* d_out, int out_size, void* d_ws, size_t ws_size,
                              hipStream_t stream) {
  const float* single = (const float*)d_in[0];
  const float* pair   = (const float*)d_in[1];
  const float* rot    = (const float*)d_in[2];
  const float* Wq  = (const float*)d_in[4];  const float* bq  = (const float*)d_in[5];
  const float* Wk  = (const float*)d_in[6];  const float* bk  = (const float*)d_in[7];
  const float* Wv  = (const float*)d_in[8];  const float* bv  = (const float*)d_in[9];
  const float* Wp  = (const float*)d_in[10]; const float* bp  = (const float*)d_in[11];
  const float* Wpq = (const float*)d_in[12]; const float* bpq = (const float*)d_in[13];
  const float* Wpk = (const float*)d_in[14]; const float* bpk = (const float*)d_in[15];
  const float* Wo  = (const float*)d_in[16]; const float* bo  = (const float*)d_in[17];
  const float* gamma = (const float*)d_in[18]; const float* beta = (const float*)d_in[19];

  float* ws   = (float*)d_ws;
  float* pb   = ws;                          // [12][N*N]
  float* q    = pb + 12L * N * N;            // [N][C]
  float* v    = q + N * C;                   // [N][C]
  float* qp   = v + N * C;                   // [N][HP]
  float* kp   = qp + N * HP;                 // [N][HP]
  float* qg   = kp + N * HP;                 // [N][HP]
  float* kcg  = qg + N * HP;                 // [12][N][48]
  float* sq   = kcg + 12L * N * 48;          // [N][12]
  float* sknh = sq + N * H;                  // [N][12]
  float* wt   = sknh + N * H;                // [N][C]

  k_qkv<<<dim3(30, 16), 256, 0, stream>>>(single, Wq, bq, Wk, bk, Wv, bv,
                                          Wpq, bpq, Wpk, bpk, q, kcg, v, qp, kp);
  k_rot<<<N, 256, 0, stream>>>(qp, kp, rot, qg, kcg, sq, sknh);
  k_pb<<<8192, 256, 0, stream>>>((const float4*)pair, Wp, bp, sq, sknh, pb);
  k_attn<<<1536, 256, 0, stream>>>(q, qg, kcg, v, pb, wt);
  k_out<<<256, 384, 0, stream>>>(wt, Wo, bo, single, gamma, beta, (float*)d_out);
}